// Round 8
// baseline (1236.388 us; speedup 1.0000x reference)
//
#include <hip/hip_runtime.h>
#include <hip/hip_bf16.h>
#include <cstddef>
#include <cstdint>

typedef __attribute__((ext_vector_type(8))) short short8;
typedef __attribute__((ext_vector_type(4))) float floatx4;
typedef __hip_bfloat16 bf16;

#define HEADS 8
#define TOK   65536
#define OUTC  256

__device__ inline float b2f(short s) {
    union { unsigned u; float f; } x;
    x.u = ((unsigned)(unsigned short)s) << 16;
    return x.f;
}

// ---------------------------------------------------------------------------
// Transpose input (B,C,32,32,32) -> token-major xbuf[(b*32768+sp)*128 + c]
// ---------------------------------------------------------------------------
__global__ __launch_bounds__(256) void transpose_in_kernel(
    const float* __restrict__ x, float* __restrict__ out)
{
    __shared__ float tile[128 * 65];
    int chunk = blockIdx.x;
    int tid = threadIdx.x;
    int b = chunk >> 9;
    int sp0 = (chunk & 511) * 64;
    #pragma unroll
    for (int l = 0; l < 32; ++l) {
        int idx = l * 256 + tid;
        int c = idx >> 6;
        int s = idx & 63;
        tile[c * 65 + s] = x[(((size_t)(b * 128 + c)) << 15) + sp0 + s];
    }
    __syncthreads();
    #pragma unroll
    for (int l = 0; l < 32; ++l) {
        int idx = l * 256 + tid;
        int s = idx >> 7;
        int c = idx & 127;
        out[((size_t)((b << 15) + sp0 + s)) * 128 + c] = tile[c * 65 + s];
    }
}

// ---------------------------------------------------------------------------
// Prep: weight fp32->bf16 conversions + dw-weight transpose + stats zero.
// ---------------------------------------------------------------------------
__global__ __launch_bounds__(256) void prep_kernel(
    const float* __restrict__ qkv_w, const float* __restrict__ proj_w,
    const float* __restrict__ fc1_w, const float* __restrict__ fc2_w,
    const float* __restrict__ pw_w, const float* __restrict__ dw_w,
    bf16* __restrict__ wbf, float* __restrict__ dwt, float* __restrict__ stats)
{
    int i = blockIdx.x * 256 + threadIdx.x;
    float v;
    if (i < 196608)       v = qkv_w[i];
    else if (i < 262144)  v = proj_w[i - 196608];
    else if (i < 524288)  v = fc1_w[i - 262144];
    else if (i < 786432)  v = fc2_w[i - 524288];
    else                  v = pw_w[i - 786432];
    wbf[i] = __float2bfloat16(v);
    if (i < 3456) {
        int c = i / 27, k = i % 27;
        dwt[k * 128 + c] = dw_w[i];
    }
    if (i < 512) stats[i] = 0.f;
}

// ---------------------------------------------------------------------------
// Pack fc1/fc2 weights into MFMA-fragment order + transpose rpb head-major.
// ---------------------------------------------------------------------------
__global__ __launch_bounds__(256) void pack_kernel(
    const float* __restrict__ fc1_w, const float* __restrict__ fc2_w,
    const float* __restrict__ rpb,
    bf16* __restrict__ pw1, bf16* __restrict__ pw2, float* __restrict__ rpbt)
{
    int t = blockIdx.x * 256 + threadIdx.x;
    int i = t >> 17;
    int rem = t & 131071;
    int type = rem >> 16;
    int idx = rem & 65535;
    int j = idx & 7, lane = (idx >> 3) & 63;
    int ln15 = lane & 15, quad = lane >> 4;
    if (type == 0) {
        int nt = (idx >> 9) & 3, kk = (idx >> 11) & 3, g = (idx >> 13) & 7;
        int row = g * 64 + nt * 16 + ln15;
        int col = kk * 32 + quad * 8 + j;
        pw1[i * 65536 + idx] = __float2bfloat16(fc1_w[(size_t)i * 65536 + row * 128 + col]);
    } else {
        int nt = (idx >> 9) & 1, ks = (idx >> 10) & 7, cc = (idx >> 13) & 1, wv = (idx >> 14) & 3;
        int row = wv * 32 + nt * 16 + ln15;
        int col = cc * 256 + ks * 32 + quad * 8 + j;
        pw2[i * 65536 + idx] = __float2bfloat16(fc2_w[(size_t)i * 65536 + row * 512 + col]);
    }
    if (t < 10976) {
        int li = t / 2744, r = t - li * 2744;
        int head = r / 343, jj = r - head * 343;
        rpbt[t] = rpb[li * 2744 + jj * 8 + head];
    }
}

// ---------------------------------------------------------------------------
// LayerNorm + cyclic shift + window partition -> bf16. 4 tokens per block.
// ---------------------------------------------------------------------------
__global__ __launch_bounds__(256) void ln_window_kernel(
    const float* __restrict__ x, bf16* __restrict__ out,
    const float* __restrict__ g, const float* __restrict__ bta, int shift)
{
    int m = blockIdx.x * 4 + (threadIdx.x >> 6);
    int lane = threadIdx.x & 63;
    int n = m & 63, w = (m >> 6) & 511, b = m >> 15;
    int ih = n >> 4, iw = (n >> 2) & 3, it = n & 3;
    int wh = w >> 6, ww = (w >> 3) & 7, wt = w & 7;
    int h  = (wh * 4 + ih + shift) & 31;
    int w2 = (ww * 4 + iw + shift) & 31;
    int t  = (wt * 4 + it + shift) & 31;
    size_t tok = ((size_t)b << 15) + ((h * 32 + w2) * 32 + t);
    const float* xp = x + tok * 128;
    float v0 = xp[lane], v1 = xp[lane + 64];
    float s = v0 + v1, sq = v0 * v0 + v1 * v1;
    #pragma unroll
    for (int o = 32; o > 0; o >>= 1) { s += __shfl_xor(s, o); sq += __shfl_xor(sq, o); }
    float mu  = s * (1.0f / 128.0f);
    float var = sq * (1.0f / 128.0f) - mu * mu;
    float rs  = rsqrtf(var + 1e-5f);
    bf16* op = out + (size_t)m * 128;
    op[lane]      = __float2bfloat16((v0 - mu) * rs * g[lane]      + bta[lane]);
    op[lane + 64] = __float2bfloat16((v1 - mu) * rs * g[lane + 64] + bta[lane + 64]);
}

// ---------------------------------------------------------------------------
// bf16 MFMA GEMM with coalesced LDS-staged epilogues.
// 128x128 tile, 256 threads = 4 waves (2x2 of 64x64), BK=32.
// mode 0: Cb[m*N+n] = bf16(v)                (LDS-staged row stores)
// mode 2: scatter-add (un-shift) into aux    (LDS-staged per-token f4 RMW)
// mode 4: BN stats: aux[n] += v, aux[256+n] += v^2
// mode 5: BN+ReLU+transpose to Cf            (LDS-transposed channel stores)
// mode 6: qkv head-major: Cb = qkvh[head][tok][48] (q16|k16|v16)
// ---------------------------------------------------------------------------
__global__ __launch_bounds__(256) void gemm_bf16_kernel(
    const bf16* __restrict__ A, const bf16* __restrict__ Bw,
    const float* __restrict__ bias, bf16* __restrict__ Cb, float* __restrict__ Cf,
    float* __restrict__ aux, const float* __restrict__ p1, const float* __restrict__ p2,
    int M, int N, int K, int mode, int shift)
{
    __shared__ __align__(16) char smem[34816];
    __shared__ float cs[128];
    __shared__ float cq[128];
    short* As = (short*)smem;
    short* Bs = (short*)(smem + 8192);
    int tid = threadIdx.x;
    int lane = tid & 63, wv = tid >> 6;
    int wm = wv >> 1, wn = wv & 1;
    int ln15 = lane & 15, quad = lane >> 4;
    int q8 = quad * 8;
    int nBase = blockIdx.x * 128;
    int mBase = blockIdx.y * 128;
    floatx4 acc[4][4] = {};

    if (mode == 4 && tid < 128) { cs[tid] = 0.f; cq[tid] = 0.f; }

    int srow = tid >> 2, scb = tid & 3;
    for (int k0 = 0; k0 < K; k0 += 32) {
        #pragma unroll
        for (int i = 0; i < 2; ++i) {
            int row = srow + i * 64;
            ((uint4*)As)[i * 256 + tid] =
                *(const uint4*)(A + (size_t)(mBase + row) * K + k0 + scb * 8);
            ((uint4*)Bs)[i * 256 + tid] =
                *(const uint4*)(Bw + (size_t)(nBase + row) * K + k0 + scb * 8);
        }
        __syncthreads();
        short8 af[4], bfr[4];
        #pragma unroll
        for (int mt = 0; mt < 4; ++mt)
            af[mt] = *(const short8*)&As[(wm * 64 + mt * 16 + ln15) * 32 + q8];
        #pragma unroll
        for (int nt = 0; nt < 4; ++nt)
            bfr[nt] = *(const short8*)&Bs[(wn * 64 + nt * 16 + ln15) * 32 + q8];
        #pragma unroll
        for (int mt = 0; mt < 4; ++mt)
            #pragma unroll
            for (int nt = 0; nt < 4; ++nt)
                acc[mt][nt] = __builtin_amdgcn_mfma_f32_16x16x32_bf16(
                    af[mt], bfr[nt], acc[mt][nt], 0, 0, 0);
        __syncthreads();
    }

    if (mode == 4) {
        #pragma unroll
        for (int nt = 0; nt < 4; ++nt) {
            int nl = wn * 64 + nt * 16 + ln15;
            float bs = bias[nBase + nl];
            float s = 0.f, sq = 0.f;
            #pragma unroll
            for (int mt = 0; mt < 4; ++mt)
                #pragma unroll
                for (int r = 0; r < 4; ++r) {
                    float v = acc[mt][nt][r] + bs;
                    s += v; sq += v * v;
                }
            atomicAdd(&cs[nl], s);
            atomicAdd(&cq[nl], sq);
        }
        __syncthreads();
        if (tid < 128) {
            atomicAdd(&aux[nBase + tid], cs[tid]);
            atomicAdd(&aux[256 + nBase + tid], cq[tid]);
        }
        return;
    }

    if (mode == 0 || mode == 6) {
        bf16* estage = (bf16*)smem;          // [128][136]
        #pragma unroll
        for (int mt = 0; mt < 4; ++mt)
            #pragma unroll
            for (int nt = 0; nt < 4; ++nt)
                #pragma unroll
                for (int r = 0; r < 4; ++r) {
                    int row = wm * 64 + mt * 16 + quad * 4 + r;
                    int col = wn * 64 + nt * 16 + ln15;
                    estage[row * 136 + col] =
                        __float2bfloat16(acc[mt][nt][r] + bias[nBase + col]);
                }
        __syncthreads();
        int row = tid >> 1, hf = tid & 1;
        if (mode == 0) {
            #pragma unroll
            for (int j = 0; j < 4; ++j) {
                int col = hf * 64 + j * 16;
                *(uint4*)(Cb + (size_t)(mBase + row) * N + nBase + col) =
                    *(const uint4*)&estage[row * 136 + col];
                *(uint4*)(Cb + (size_t)(mBase + row) * N + nBase + col + 8) =
                    *(const uint4*)&estage[row * 136 + col + 8];
            }
        } else {
            // head-major qkv: dst[(head*TOK + m)*48 + p*16 + d]
            int p = nBase >> 7;              // 0=q 1=k 2=v
            #pragma unroll
            for (int j = 0; j < 4; ++j) {
                int col = hf * 64 + j * 16;
                int head = hf * 4 + j;
                bf16* dst = Cb + ((size_t)head * TOK + mBase + row) * 48 + p * 16;
                *(uint4*)dst       = *(const uint4*)&estage[row * 136 + col];
                *(uint4*)(dst + 8) = *(const uint4*)&estage[row * 136 + col + 8];
            }
        }
        return;
    }

    if (mode == 2) {
        float* fstage = (float*)smem;        // [64][132]
        #pragma unroll
        for (int hf = 0; hf < 2; ++hf) {
            if (wm == hf) {
                #pragma unroll
                for (int mt = 0; mt < 4; ++mt)
                    #pragma unroll
                    for (int nt = 0; nt < 4; ++nt)
                        #pragma unroll
                        for (int r = 0; r < 4; ++r) {
                            int ml = mt * 16 + quad * 4 + r;
                            int col = wn * 64 + nt * 16 + ln15;
                            fstage[ml * 132 + col] = acc[mt][nt][r] + bias[col];
                        }
            }
            __syncthreads();
            int tl = tid >> 2, part = tid & 3;
            int g = mBase + hf * 64 + tl;
            int n_ = g & 63, w = (g >> 6) & 511, b = g >> 15;
            int ih = n_ >> 4, iw = (n_ >> 2) & 3, it = n_ & 3;
            int wh = w >> 6, ww = (w >> 3) & 7, wt = w & 7;
            int h  = (wh * 4 + ih + shift) & 31;
            int w2 = (ww * 4 + iw + shift) & 31;
            int t  = (wt * 4 + it + shift) & 31;
            size_t tok = ((size_t)b << 15) + ((h * 32 + w2) * 32 + t);
            float* dst = aux + tok * 128 + part * 32;
            #pragma unroll
            for (int j = 0; j < 8; ++j) {
                float4 a = *(float4*)(dst + j * 4);
                float4 l = *(const float4*)&fstage[tl * 132 + part * 32 + j * 4];
                a.x += l.x; a.y += l.y; a.z += l.z; a.w += l.w;
                *(float4*)(dst + j * 4) = a;
            }
            __syncthreads();
        }
        return;
    }

    // mode 5: BN + ReLU + transposed store
    {
        float* fstage = (float*)smem;        // [64 nn][132 sp]
        int b = mBase >> 15, sp0 = mBase & 32767;
        #pragma unroll
        for (int hf = 0; hf < 2; ++hf) {
            if (wn == hf) {
                #pragma unroll
                for (int nt = 0; nt < 4; ++nt) {
                    int ncol = nt * 16 + ln15;
                    int nn = nBase + hf * 64 + ncol;
                    float mean = aux[nn] * (1.0f / 65536.0f);
                    float var  = aux[256 + nn] * (1.0f / 65536.0f) - mean * mean;
                    float sc = rsqrtf(var + 1e-5f) * p1[nn];
                    float off = p2[nn] + bias[nn] * sc - mean * sc;
                    #pragma unroll
                    for (int mt = 0; mt < 4; ++mt)
                        #pragma unroll
                        for (int r = 0; r < 4; ++r) {
                            int ml = wm * 64 + mt * 16 + quad * 4 + r;
                            float y = acc[mt][nt][r] * sc + off;
                            fstage[ncol * 132 + ml] = fmaxf(y, 0.f);
                        }
                }
            }
            __syncthreads();
            int nl = tid >> 2, part = tid & 3;
            int nn = nBase + hf * 64 + nl;
            float* dst = Cf + (((size_t)(b * 256 + nn)) << 15) + sp0 + part * 32;
            #pragma unroll
            for (int j = 0; j < 8; ++j)
                *(float4*)(dst + j * 4) = *(const float4*)&fstage[nl * 132 + part * 32 + j * 4];
            __syncthreads();
        }
    }
}

// ---------------------------------------------------------------------------
// Fused MLP v3: LN2 + fc1 + GELU + fc2 + residual. 64 tokens/block.
// ---------------------------------------------------------------------------
__global__ __launch_bounds__(256) void mlp_kernel(
    float* __restrict__ xbuf, const float* __restrict__ g, const float* __restrict__ bta,
    const bf16* __restrict__ pw1, const float* __restrict__ b1,
    const bf16* __restrict__ pw2, const float* __restrict__ b2,
    bf16* __restrict__ xout16)
{
    __shared__ __align__(16) bf16 aln[64 * 136];     // 17.4 KB
    __shared__ __align__(16) bf16 hidc[64 * 264];    // 33.0 KB (also ostage [64][132] f32)
    float* ostage = (float*)hidc;
    int tid = threadIdx.x;
    int lane = tid & 63, wv = tid >> 6;
    int ln15 = lane & 15, quad = lane >> 4;
    int q8 = quad * 8;
    size_t tok0 = (size_t)blockIdx.x * 64;

    #pragma unroll
    for (int itk = 0; itk < 16; ++itk) {
        int t = wv * 16 + itk;
        const float* xp = xbuf + (tok0 + t) * 128;
        float v0 = xp[lane], v1 = xp[lane + 64];
        float s = v0 + v1, sq = v0 * v0 + v1 * v1;
        #pragma unroll
        for (int o = 32; o > 0; o >>= 1) { s += __shfl_xor(s, o); sq += __shfl_xor(sq, o); }
        float mu  = s * (1.0f / 128.0f);
        float var = sq * (1.0f / 128.0f) - mu * mu;
        float rs  = rsqrtf(var + 1e-5f);
        aln[t * 136 + lane]      = __float2bfloat16((v0 - mu) * rs * g[lane]      + bta[lane]);
        aln[t * 136 + lane + 64] = __float2bfloat16((v1 - mu) * rs * g[lane + 64] + bta[lane + 64]);
    }
    __syncthreads();

    floatx4 acc2[4][2] = {};
    #pragma unroll
    for (int cc = 0; cc < 2; ++cc) {
        floatx4 acc[4][4] = {};
        const bf16* p1w = pw1 + (size_t)(cc * 4 + wv) * 8192;
        #pragma unroll
        for (int kk = 0; kk < 4; ++kk) {
            short8 af[4], bfr[4];
            #pragma unroll
            for (int mt = 0; mt < 4; ++mt)
                af[mt] = *(const short8*)&aln[(mt * 16 + ln15) * 136 + kk * 32 + q8];
            #pragma unroll
            for (int nt = 0; nt < 4; ++nt)
                bfr[nt] = *(const short8*)(p1w + kk * 2048 + nt * 512 + lane * 8);
            #pragma unroll
            for (int mt = 0; mt < 4; ++mt)
                #pragma unroll
                for (int nt = 0; nt < 4; ++nt)
                    acc[mt][nt] = __builtin_amdgcn_mfma_f32_16x16x32_bf16(
                        af[mt], bfr[nt], acc[mt][nt], 0, 0, 0);
        }
        if (cc) __syncthreads();
        #pragma unroll
        for (int mt = 0; mt < 4; ++mt)
            #pragma unroll
            for (int nt = 0; nt < 4; ++nt)
                #pragma unroll
                for (int r = 0; r < 4; ++r) {
                    int m = mt * 16 + quad * 4 + r;
                    int ncl = wv * 64 + nt * 16 + ln15;
                    float v = acc[mt][nt][r] + b1[cc * 256 + ncl];
                    v = 0.5f * v * (1.0f + erff(v * 0.70710678118654752f));
                    hidc[m * 264 + ncl] = __float2bfloat16(v);
                }
        __syncthreads();
        const bf16* p2w = pw2 + (size_t)(wv * 2 + cc) * 8192;
        #pragma unroll
        for (int ks = 0; ks < 8; ++ks) {
            short8 af[4], bfr[2];
            #pragma unroll
            for (int mt = 0; mt < 4; ++mt)
                af[mt] = *(const short8*)&hidc[(mt * 16 + ln15) * 264 + ks * 32 + q8];
            #pragma unroll
            for (int nt = 0; nt < 2; ++nt)
                bfr[nt] = *(const short8*)(p2w + ks * 1024 + nt * 512 + lane * 8);
            #pragma unroll
            for (int mt = 0; mt < 4; ++mt)
                #pragma unroll
                for (int nt = 0; nt < 2; ++nt)
                    acc2[mt][nt] = __builtin_amdgcn_mfma_f32_16x16x32_bf16(
                        af[mt], bfr[nt], acc2[mt][nt], 0, 0, 0);
        }
    }
    __syncthreads();

    #pragma unroll
    for (int mt = 0; mt < 4; ++mt)
        #pragma unroll
        for (int nt = 0; nt < 2; ++nt)
            #pragma unroll
            for (int r = 0; r < 4; ++r) {
                int m = mt * 16 + quad * 4 + r;
                int n = wv * 32 + nt * 16 + ln15;
                ostage[m * 132 + n] = acc2[mt][nt][r] + b2[n];
            }
    __syncthreads();

    #pragma unroll
    for (int jj = 0; jj < 8; ++jj) {
        int idx = (jj * 256 + tid) * 4;
        int t = idx >> 7, c = idx & 127;
        float4 v = *(const float4*)(xbuf + tok0 * 128 + idx);
        float4 o = *(const float4*)&ostage[t * 132 + c];
        v.x += o.x; v.y += o.y; v.z += o.z; v.w += o.w;
        *(float4*)(xbuf + tok0 * 128 + idx) = v;
        if (xout16) {
            __align__(8) bf16 hh[4];
            hh[0] = __float2bfloat16(v.x); hh[1] = __float2bfloat16(v.y);
            hh[2] = __float2bfloat16(v.z); hh[3] = __float2bfloat16(v.w);
            *(uint2*)(xout16 + tok0 * 128 + idx) = *(const uint2*)hh;
        }
    }
}

// ---------------------------------------------------------------------------
// Windowed attention, head-major qkvh[head][tok][48] (q16|k16|v16).
// One block per (window, head); each lane reads its token's contiguous 96 B.
// ---------------------------------------------------------------------------
__global__ __launch_bounds__(64) void attn_kernel(
    const bf16* __restrict__ qkvh, const float* __restrict__ rpbt,
    bf16* __restrict__ outp, int shift)
{
    __shared__ float kt[64][16];
    __shared__ float vt[64][16];
    __shared__ float rp[343];
    __shared__ int   cnt[64];
    int blk = blockIdx.x;
    int head = blk & 7;
    int lw = blk >> 3;
    int i = threadIdx.x;
    const short8* sp = (const short8*)(qkvh + ((size_t)head * TOK + lw * 64 + i) * 48);
    short8 q0 = sp[0], q1 = sp[1];
    short8 k0 = sp[2], k1 = sp[3];
    short8 v0 = sp[4], v1 = sp[5];
    float q[16];
    #pragma unroll
    for (int d = 0; d < 8; ++d) {
        q[d] = b2f(q0[d]) * 0.25f;  q[d + 8] = b2f(q1[d]) * 0.25f;
        kt[i][d] = b2f(k0[d]);      kt[i][d + 8] = b2f(k1[d]);
        vt[i][d] = b2f(v0[d]);      vt[i][d + 8] = b2f(v1[d]);
    }
    for (int j = i; j < 343; j += 64) rp[j] = rpbt[head * 343 + j];
    int w = lw & 511;
    int ih = i >> 4, iw = (i >> 2) & 3, it = i & 3;
    if (shift) {
        int wh = w >> 6, ww = (w >> 3) & 7, wt = w & 7;
        int h = wh * 4 + ih, w2 = ww * 4 + iw, t = wt * 4 + it;
        int rh = (h  < 28) ? 0 : ((h  < 30) ? 1 : 2);
        int rw = (w2 < 28) ? 0 : ((w2 < 30) ? 1 : 2);
        int rt = (t  < 28) ? 0 : ((t  < 30) ? 1 : 2);
        cnt[i] = (rh * 3 + rw) * 3 + rt;
    }
    __syncthreads();
    float logits[64];
    int ci = shift ? cnt[i] : 0;
    #pragma unroll
    for (int j = 0; j < 64; ++j) {
        float d0 = 0.f;
        #pragma unroll
        for (int d = 0; d < 16; ++d) d0 += q[d] * kt[j][d];
        int jh = j >> 4, jw = (j >> 2) & 3, jt = j & 3;
        int ridx = ((ih - jh + 3) * 7 + (iw - jw + 3)) * 7 + (it - jt + 3);
        d0 += rp[ridx];
        if (shift && cnt[j] != ci) d0 -= 100.0f;
        logits[j] = d0;
    }
    float mx = -1e30f;
    #pragma unroll
    for (int j = 0; j < 64; ++j) mx = fmaxf(mx, logits[j]);
    float ssum = 0.f;
    #pragma unroll
    for (int j = 0; j < 64; ++j) { float e = __expf(logits[j] - mx); logits[j] = e; ssum += e; }
    float inv = 1.0f / ssum;
    float o[16] = {};
    #pragma unroll
    for (int j = 0; j < 64; ++j) {
        float p = logits[j] * inv;
        #pragma unroll
        for (int d = 0; d < 16; ++d) o[d] += p * vt[j][d];
    }
    bf16* op = outp + (size_t)(lw * 64 + i) * 128 + head * 16;
    #pragma unroll
    for (int d = 0; d < 16; ++d) op[d] = __float2bfloat16(o[d]);
}

// ---------------------------------------------------------------------------
// Depthwise 3x3x3 conv, bf16 in/out, register t-window reuse.
// ---------------------------------------------------------------------------
__global__ __launch_bounds__(512) void dwconv_kernel(
    const bf16* __restrict__ x, const float* __restrict__ dwt,
    const float* __restrict__ bias, bf16* __restrict__ out)
{
    int blk = blockIdx.x;
    int b = blk >> 10;
    int h = (blk >> 5) & 31;
    int w = blk & 31;
    int tid = threadIdx.x;
    int c = tid & 127;
    int t0 = (tid >> 7) * 8;
    float acc[8];
    float bs = bias[c];
    #pragma unroll
    for (int o = 0; o < 8; ++o) acc[o] = bs;
    #pragma unroll
    for (int kh = 0; kh < 3; ++kh) {
        int hh = h + kh - 1;
        if (hh < 0 || hh > 31) continue;
        #pragma unroll
        for (int kw = 0; kw < 3; ++kw) {
            int ww = w + kw - 1;
            if (ww < 0 || ww > 31) continue;
            const bf16* px = x + (((size_t)(b << 15) + (hh * 32 + ww) * 32) * 128) + c;
            float v[10];
            #pragma unroll
            for (int u = 0; u < 10; ++u) {
                int tt = t0 - 1 + u;
                v[u] = (tt >= 0 && tt < 32) ? __bfloat162float(px[(size_t)tt * 128]) : 0.f;
            }
            float w0 = dwt[((kh * 3 + kw) * 3 + 0) * 128 + c];
            float w1 = dwt[((kh * 3 + kw) * 3 + 1) * 128 + c];
            float w2 = dwt[((kh * 3 + kw) * 3 + 2) * 128 + c];
            #pragma unroll
            for (int o = 0; o < 8; ++o)
                acc[o] += v[o] * w0 + v[o + 1] * w1 + v[o + 2] * w2;
        }
    }
    bf16* po = out + (((size_t)(b << 15) + (h * 32 + w) * 32 + t0) * 128) + c;
    #pragma unroll
    for (int o = 0; o < 8; ++o) po[(size_t)o * 128] = __float2bfloat16(acc[o]);
}

// ---------------------------------------------------------------------------
extern "C" void kernel_launch(void* const* d_in, const int* in_sizes, int n_in,
                              void* d_out, int out_size, void* d_ws, size_t ws_size,
                              hipStream_t stream)
{
    const float* x_in    = (const float*)d_in[0];
    const float* norm1_g = (const float*)d_in[1];
    const float* norm1_b = (const float*)d_in[2];
    const float* qkv_w   = (const float*)d_in[3];
    const float* qkv_b   = (const float*)d_in[4];
    const float* proj_w  = (const float*)d_in[5];
    const float* proj_b  = (const float*)d_in[6];
    const float* rpb     = (const float*)d_in[7];
    const float* norm2_g = (const float*)d_in[8];
    const float* norm2_b = (const float*)d_in[9];
    const float* fc1_w   = (const float*)d_in[10];
    const float* fc1_b   = (const float*)d_in[11];
    const float* fc2_w   = (const float*)d_in[12];
    const float* fc2_b   = (const float*)d_in[13];
    const float* dw_w    = (const float*)d_in[14];
    const float* dw_b    = (const float*)d_in[15];
    const float* pw_w    = (const float*)d_in[16];
    const float* pw_b    = (const float*)d_in[17];
    const float* bn_g    = (const float*)d_in[18];
    const float* bn_b    = (const float*)d_in[19];
    float* out = (float*)d_out;

    char* ws = (char*)d_ws;
    float* xbuf   = (float*)ws;                          // [0,32MB)   fp32 [TOK,128]
    bf16*  wbf    = (bf16*)(ws + 33554432ULL);           // [32,34MB)  bf16 weights
    float* dwt    = (float*)(ws + 35651584ULL);          // 27x128 fp32
    float* stats  = (float*)(ws + 35717120ULL);          // 2 KB
    bf16*  pw1    = (bf16*)(ws + 35782656ULL);           // 512 KB packed fc1
    bf16*  pw2    = (bf16*)(ws + 36306944ULL);           // 512 KB packed fc2
    float* rpbt   = (float*)(ws + 36831232ULL);          // 44 KB
    bf16*  lnbuf  = (bf16*)(ws + 37748736ULL);           // [36,52MB)  [TOK,128]
    bf16*  attnbuf= (bf16*)(ws + 54525952ULL);           // [52,68MB)  [TOK,128]
    bf16*  qkvh   = (bf16*)(ws + 71303168ULL);           // [68,116MB) [8][TOK][48]
    bf16*  dwbuf  = attnbuf;
    bf16*  dcbuf  = lnbuf;

    bf16* wqkv  = wbf;                 // 4 x 384 x 128
    bf16* wproj = wbf + 196608;        // 4 x 128 x 128
    bf16* wpw   = wbf + 786432;        // 256 x 128

    hipLaunchKernelGGL(prep_kernel, dim3(3200), dim3(256), 0, stream,
                       qkv_w, proj_w, fc1_w, fc2_w, pw_w, dw_w, wbf, dwt, stats);
    hipLaunchKernelGGL(pack_kernel, dim3(2048), dim3(256), 0, stream,
                       fc1_w, fc2_w, rpb, pw1, pw2, rpbt);
    hipLaunchKernelGGL(transpose_in_kernel, dim3(1024), dim3(256), 0, stream, x_in, xbuf);

    const int shifts[4] = {0, 2, 0, 2};
    for (int i = 0; i < 4; ++i) {
        int s = shifts[i];
        // --- attention half ---
        hipLaunchKernelGGL(ln_window_kernel, dim3(TOK / 4), dim3(256), 0, stream,
                           xbuf, lnbuf, norm1_g + i * 128, norm1_b + i * 128, s);
        hipLaunchKernelGGL(gemm_bf16_kernel, dim3(3, TOK / 128), dim3(256), 0, stream,
                           lnbuf, wqkv + (size_t)i * 49152, qkv_b + i * 384,
                           qkvh, (float*)nullptr, (float*)nullptr,
                           (const float*)nullptr, (const float*)nullptr,
                           TOK, 384, 128, 6, 0);
        hipLaunchKernelGGL(attn_kernel, dim3(1024 * HEADS), dim3(64), 0, stream,
                           qkvh, rpbt + i * 2744, attnbuf, s);
        hipLaunchKernelGGL(gemm_bf16_kernel, dim3(1, TOK / 128), dim3(256), 0, stream,
                           attnbuf, wproj + (size_t)i * 16384, proj_b + i * 128,
                           (bf16*)nullptr, (float*)nullptr, xbuf,
                           (const float*)nullptr, (const float*)nullptr,
                           TOK, 128, 128, 2, s);
        // --- fused MLP ---
        hipLaunchKernelGGL(mlp_kernel, dim3(TOK / 64), dim3(256), 0, stream,
                           xbuf, norm2_g + i * 128, norm2_b + i * 128,
                           pw1 + (size_t)i * 65536, fc1_b + i * 512,
                           pw2 + (size_t)i * 65536, fc2_b + i * 128,
                           (i == 3) ? dwbuf : (bf16*)nullptr);
    }

    // connectBlock
    hipLaunchKernelGGL(dwconv_kernel, dim3(2048), dim3(512), 0, stream,
                       dwbuf, dwt, dw_b, dcbuf);
    hipLaunchKernelGGL(gemm_bf16_kernel, dim3(OUTC / 128, TOK / 128), dim3(256), 0, stream,
                       dcbuf, wpw, pw_b,
                       (bf16*)nullptr, (float*)nullptr, stats,
                       (const float*)nullptr, (const float*)nullptr,
                       TOK, OUTC, 128, 4, 0);
    hipLaunchKernelGGL(gemm_bf16_kernel, dim3(OUTC / 128, TOK / 128), dim3(256), 0, stream,
                       dcbuf, wpw, pw_b,
                       (bf16*)nullptr, out, stats,
                       bn_g, bn_b,
                       TOK, OUTC, 128, 5, 0);
}

// Round 9
// 1056.544 us; speedup vs baseline: 1.1702x; 1.1702x over previous
//
#include <hip/hip_runtime.h>
#include <hip/hip_bf16.h>
#include <cstddef>
#include <cstdint>

typedef __attribute__((ext_vector_type(8))) short short8;
typedef __attribute__((ext_vector_type(4))) float floatx4;
typedef __hip_bfloat16 bf16;

#define HEADS 8
#define TOK   65536
#define OUTC  256

__device__ inline float b2f(short s) {
    union { unsigned u; float f; } x;
    x.u = ((unsigned)(unsigned short)s) << 16;
    return x.f;
}

// ---------------------------------------------------------------------------
// Transpose input (B,C,32,32,32) -> token-major xbuf[(b*32768+sp)*128 + c]
// ---------------------------------------------------------------------------
__global__ __launch_bounds__(256) void transpose_in_kernel(
    const float* __restrict__ x, float* __restrict__ out)
{
    __shared__ float tile[128 * 65];
    int chunk = blockIdx.x;
    int tid = threadIdx.x;
    int b = chunk >> 9;
    int sp0 = (chunk & 511) * 64;
    #pragma unroll
    for (int l = 0; l < 32; ++l) {
        int idx = l * 256 + tid;
        int c = idx >> 6;
        int s = idx & 63;
        tile[c * 65 + s] = x[(((size_t)(b * 128 + c)) << 15) + sp0 + s];
    }
    __syncthreads();
    #pragma unroll
    for (int l = 0; l < 32; ++l) {
        int idx = l * 256 + tid;
        int s = idx >> 7;
        int c = idx & 127;
        out[((size_t)((b << 15) + sp0 + s)) * 128 + c] = tile[c * 65 + s];
    }
}

// ---------------------------------------------------------------------------
// Prep: weight fp32->bf16 conversions + dw-weight transpose + stats zero.
// ---------------------------------------------------------------------------
__global__ __launch_bounds__(256) void prep_kernel(
    const float* __restrict__ qkv_w, const float* __restrict__ proj_w,
    const float* __restrict__ fc1_w, const float* __restrict__ fc2_w,
    const float* __restrict__ pw_w, const float* __restrict__ dw_w,
    bf16* __restrict__ wbf, float* __restrict__ dwt, float* __restrict__ stats)
{
    int i = blockIdx.x * 256 + threadIdx.x;
    float v;
    if (i < 196608)       v = qkv_w[i];
    else if (i < 262144)  v = proj_w[i - 196608];
    else if (i < 524288)  v = fc1_w[i - 262144];
    else if (i < 786432)  v = fc2_w[i - 524288];
    else                  v = pw_w[i - 786432];
    wbf[i] = __float2bfloat16(v);
    if (i < 3456) {
        int c = i / 27, k = i % 27;
        dwt[k * 128 + c] = dw_w[i];
    }
    if (i < 512) stats[i] = 0.f;
}

// ---------------------------------------------------------------------------
// Pack fc1/fc2 weights into MFMA-fragment order + transpose rpb head-major.
// ---------------------------------------------------------------------------
__global__ __launch_bounds__(256) void pack_kernel(
    const float* __restrict__ fc1_w, const float* __restrict__ fc2_w,
    const float* __restrict__ rpb,
    bf16* __restrict__ pw1, bf16* __restrict__ pw2, float* __restrict__ rpbt)
{
    int t = blockIdx.x * 256 + threadIdx.x;
    int i = t >> 17;
    int rem = t & 131071;
    int type = rem >> 16;
    int idx = rem & 65535;
    int j = idx & 7, lane = (idx >> 3) & 63;
    int ln15 = lane & 15, quad = lane >> 4;
    if (type == 0) {
        int nt = (idx >> 9) & 3, kk = (idx >> 11) & 3, g = (idx >> 13) & 7;
        int row = g * 64 + nt * 16 + ln15;
        int col = kk * 32 + quad * 8 + j;
        pw1[i * 65536 + idx] = __float2bfloat16(fc1_w[(size_t)i * 65536 + row * 128 + col]);
    } else {
        int nt = (idx >> 9) & 1, ks = (idx >> 10) & 7, cc = (idx >> 13) & 1, wv = (idx >> 14) & 3;
        int row = wv * 32 + nt * 16 + ln15;
        int col = cc * 256 + ks * 32 + quad * 8 + j;
        pw2[i * 65536 + idx] = __float2bfloat16(fc2_w[(size_t)i * 65536 + row * 512 + col]);
    }
    if (t < 10976) {
        int li = t / 2744, r = t - li * 2744;
        int head = r / 343, jj = r - head * 343;
        rpbt[t] = rpb[li * 2744 + jj * 8 + head];
    }
}

// ---------------------------------------------------------------------------
// LayerNorm + cyclic shift + window partition -> bf16. 4 tokens per block.
// ---------------------------------------------------------------------------
__global__ __launch_bounds__(256) void ln_window_kernel(
    const float* __restrict__ x, bf16* __restrict__ out,
    const float* __restrict__ g, const float* __restrict__ bta, int shift)
{
    int m = blockIdx.x * 4 + (threadIdx.x >> 6);
    int lane = threadIdx.x & 63;
    int n = m & 63, w = (m >> 6) & 511, b = m >> 15;
    int ih = n >> 4, iw = (n >> 2) & 3, it = n & 3;
    int wh = w >> 6, ww = (w >> 3) & 7, wt = w & 7;
    int h  = (wh * 4 + ih + shift) & 31;
    int w2 = (ww * 4 + iw + shift) & 31;
    int t  = (wt * 4 + it + shift) & 31;
    size_t tok = ((size_t)b << 15) + ((h * 32 + w2) * 32 + t);
    const float* xp = x + tok * 128;
    float v0 = xp[lane], v1 = xp[lane + 64];
    float s = v0 + v1, sq = v0 * v0 + v1 * v1;
    #pragma unroll
    for (int o = 32; o > 0; o >>= 1) { s += __shfl_xor(s, o); sq += __shfl_xor(sq, o); }
    float mu  = s * (1.0f / 128.0f);
    float var = sq * (1.0f / 128.0f) - mu * mu;
    float rs  = rsqrtf(var + 1e-5f);
    bf16* op = out + (size_t)m * 128;
    op[lane]      = __float2bfloat16((v0 - mu) * rs * g[lane]      + bta[lane]);
    op[lane + 64] = __float2bfloat16((v1 - mu) * rs * g[lane + 64] + bta[lane + 64]);
}

// ---------------------------------------------------------------------------
// bf16 MFMA GEMM with coalesced LDS-staged epilogues.
// 128x128 tile, 256 threads = 4 waves (2x2 of 64x64), BK=32.
// mode 0: Cb[m*N+n] = bf16(v)                (LDS-staged row stores)
// mode 2: scatter-add (un-shift) into aux    (LDS-staged per-token f4 RMW)
// mode 4: BN stats: aux[n] += v, aux[256+n] += v^2
// mode 5: BN+ReLU+transpose to Cf            (LDS-transposed channel stores)
// ---------------------------------------------------------------------------
__global__ __launch_bounds__(256) void gemm_bf16_kernel(
    const bf16* __restrict__ A, const bf16* __restrict__ Bw,
    const float* __restrict__ bias, bf16* __restrict__ Cb, float* __restrict__ Cf,
    float* __restrict__ aux, const float* __restrict__ p1, const float* __restrict__ p2,
    int M, int N, int K, int mode, int shift)
{
    __shared__ __align__(16) char smem[34816];
    __shared__ float cs[128];
    __shared__ float cq[128];
    short* As = (short*)smem;
    short* Bs = (short*)(smem + 8192);
    int tid = threadIdx.x;
    int lane = tid & 63, wv = tid >> 6;
    int wm = wv >> 1, wn = wv & 1;
    int ln15 = lane & 15, quad = lane >> 4;
    int q8 = quad * 8;
    int nBase = blockIdx.x * 128;
    int mBase = blockIdx.y * 128;
    floatx4 acc[4][4] = {};

    if (mode == 4 && tid < 128) { cs[tid] = 0.f; cq[tid] = 0.f; }

    int srow = tid >> 2, scb = tid & 3;
    for (int k0 = 0; k0 < K; k0 += 32) {
        #pragma unroll
        for (int i = 0; i < 2; ++i) {
            int row = srow + i * 64;
            ((uint4*)As)[i * 256 + tid] =
                *(const uint4*)(A + (size_t)(mBase + row) * K + k0 + scb * 8);
            ((uint4*)Bs)[i * 256 + tid] =
                *(const uint4*)(Bw + (size_t)(nBase + row) * K + k0 + scb * 8);
        }
        __syncthreads();
        short8 af[4], bfr[4];
        #pragma unroll
        for (int mt = 0; mt < 4; ++mt)
            af[mt] = *(const short8*)&As[(wm * 64 + mt * 16 + ln15) * 32 + q8];
        #pragma unroll
        for (int nt = 0; nt < 4; ++nt)
            bfr[nt] = *(const short8*)&Bs[(wn * 64 + nt * 16 + ln15) * 32 + q8];
        #pragma unroll
        for (int mt = 0; mt < 4; ++mt)
            #pragma unroll
            for (int nt = 0; nt < 4; ++nt)
                acc[mt][nt] = __builtin_amdgcn_mfma_f32_16x16x32_bf16(
                    af[mt], bfr[nt], acc[mt][nt], 0, 0, 0);
        __syncthreads();
    }

    if (mode == 4) {
        #pragma unroll
        for (int nt = 0; nt < 4; ++nt) {
            int nl = wn * 64 + nt * 16 + ln15;
            float bs = bias[nBase + nl];
            float s = 0.f, sq = 0.f;
            #pragma unroll
            for (int mt = 0; mt < 4; ++mt)
                #pragma unroll
                for (int r = 0; r < 4; ++r) {
                    float v = acc[mt][nt][r] + bs;
                    s += v; sq += v * v;
                }
            atomicAdd(&cs[nl], s);
            atomicAdd(&cq[nl], sq);
        }
        __syncthreads();
        if (tid < 128) {
            atomicAdd(&aux[nBase + tid], cs[tid]);
            atomicAdd(&aux[256 + nBase + tid], cq[tid]);
        }
        return;
    }

    if (mode == 0) {
        bf16* estage = (bf16*)smem;          // [128][136]
        #pragma unroll
        for (int mt = 0; mt < 4; ++mt)
            #pragma unroll
            for (int nt = 0; nt < 4; ++nt)
                #pragma unroll
                for (int r = 0; r < 4; ++r) {
                    int row = wm * 64 + mt * 16 + quad * 4 + r;
                    int col = wn * 64 + nt * 16 + ln15;
                    estage[row * 136 + col] =
                        __float2bfloat16(acc[mt][nt][r] + bias[nBase + col]);
                }
        __syncthreads();
        int row = tid >> 1, hf = tid & 1;
        #pragma unroll
        for (int j = 0; j < 4; ++j) {
            int col = hf * 64 + j * 16;
            *(uint4*)(Cb + (size_t)(mBase + row) * N + nBase + col) =
                *(const uint4*)&estage[row * 136 + col];
            *(uint4*)(Cb + (size_t)(mBase + row) * N + nBase + col + 8) =
                *(const uint4*)&estage[row * 136 + col + 8];
        }
        return;
    }

    if (mode == 2) {
        float* fstage = (float*)smem;        // [64][132]
        #pragma unroll
        for (int hf = 0; hf < 2; ++hf) {
            if (wm == hf) {
                #pragma unroll
                for (int mt = 0; mt < 4; ++mt)
                    #pragma unroll
                    for (int nt = 0; nt < 4; ++nt)
                        #pragma unroll
                        for (int r = 0; r < 4; ++r) {
                            int ml = mt * 16 + quad * 4 + r;
                            int col = wn * 64 + nt * 16 + ln15;
                            fstage[ml * 132 + col] = acc[mt][nt][r] + bias[col];
                        }
            }
            __syncthreads();
            int tl = tid >> 2, part = tid & 3;
            int g = mBase + hf * 64 + tl;
            int n_ = g & 63, w = (g >> 6) & 511, b = g >> 15;
            int ih = n_ >> 4, iw = (n_ >> 2) & 3, it = n_ & 3;
            int wh = w >> 6, ww = (w >> 3) & 7, wt = w & 7;
            int h  = (wh * 4 + ih + shift) & 31;
            int w2 = (ww * 4 + iw + shift) & 31;
            int t  = (wt * 4 + it + shift) & 31;
            size_t tok = ((size_t)b << 15) + ((h * 32 + w2) * 32 + t);
            float* dst = aux + tok * 128 + part * 32;
            #pragma unroll
            for (int j = 0; j < 8; ++j) {
                float4 a = *(float4*)(dst + j * 4);
                float4 l = *(const float4*)&fstage[tl * 132 + part * 32 + j * 4];
                a.x += l.x; a.y += l.y; a.z += l.z; a.w += l.w;
                *(float4*)(dst + j * 4) = a;
            }
            __syncthreads();
        }
        return;
    }

    // mode 5: BN + ReLU + transposed store
    {
        float* fstage = (float*)smem;        // [64 nn][132 sp]
        int b = mBase >> 15, sp0 = mBase & 32767;
        #pragma unroll
        for (int hf = 0; hf < 2; ++hf) {
            if (wn == hf) {
                #pragma unroll
                for (int nt = 0; nt < 4; ++nt) {
                    int ncol = nt * 16 + ln15;
                    int nn = nBase + hf * 64 + ncol;
                    float mean = aux[nn] * (1.0f / 65536.0f);
                    float var  = aux[256 + nn] * (1.0f / 65536.0f) - mean * mean;
                    float sc = rsqrtf(var + 1e-5f) * p1[nn];
                    float off = p2[nn] + bias[nn] * sc - mean * sc;
                    #pragma unroll
                    for (int mt = 0; mt < 4; ++mt)
                        #pragma unroll
                        for (int r = 0; r < 4; ++r) {
                            int ml = wm * 64 + mt * 16 + quad * 4 + r;
                            float y = acc[mt][nt][r] * sc + off;
                            fstage[ncol * 132 + ml] = fmaxf(y, 0.f);
                        }
                }
            }
            __syncthreads();
            int nl = tid >> 2, part = tid & 3;
            int nn = nBase + hf * 64 + nl;
            float* dst = Cf + (((size_t)(b * 256 + nn)) << 15) + sp0 + part * 32;
            #pragma unroll
            for (int j = 0; j < 8; ++j)
                *(float4*)(dst + j * 4) = *(const float4*)&fstage[nl * 132 + part * 32 + j * 4];
            __syncthreads();
        }
    }
}

// ---------------------------------------------------------------------------
// Fused MLP v3: LN2 + fc1 + GELU + fc2 + residual. 64 tokens/block.
// ---------------------------------------------------------------------------
__global__ __launch_bounds__(256) void mlp_kernel(
    float* __restrict__ xbuf, const float* __restrict__ g, const float* __restrict__ bta,
    const bf16* __restrict__ pw1, const float* __restrict__ b1,
    const bf16* __restrict__ pw2, const float* __restrict__ b2,
    bf16* __restrict__ xout16)
{
    __shared__ __align__(16) bf16 aln[64 * 136];     // 17.4 KB
    __shared__ __align__(16) bf16 hidc[64 * 264];    // 33.0 KB (also ostage [64][132] f32)
    float* ostage = (float*)hidc;
    int tid = threadIdx.x;
    int lane = tid & 63, wv = tid >> 6;
    int ln15 = lane & 15, quad = lane >> 4;
    int q8 = quad * 8;
    size_t tok0 = (size_t)blockIdx.x * 64;

    #pragma unroll
    for (int itk = 0; itk < 16; ++itk) {
        int t = wv * 16 + itk;
        const float* xp = xbuf + (tok0 + t) * 128;
        float v0 = xp[lane], v1 = xp[lane + 64];
        float s = v0 + v1, sq = v0 * v0 + v1 * v1;
        #pragma unroll
        for (int o = 32; o > 0; o >>= 1) { s += __shfl_xor(s, o); sq += __shfl_xor(sq, o); }
        float mu  = s * (1.0f / 128.0f);
        float var = sq * (1.0f / 128.0f) - mu * mu;
        float rs  = rsqrtf(var + 1e-5f);
        aln[t * 136 + lane]      = __float2bfloat16((v0 - mu) * rs * g[lane]      + bta[lane]);
        aln[t * 136 + lane + 64] = __float2bfloat16((v1 - mu) * rs * g[lane + 64] + bta[lane + 64]);
    }
    __syncthreads();

    floatx4 acc2[4][2] = {};
    #pragma unroll
    for (int cc = 0; cc < 2; ++cc) {
        floatx4 acc[4][4] = {};
        const bf16* p1w = pw1 + (size_t)(cc * 4 + wv) * 8192;
        #pragma unroll
        for (int kk = 0; kk < 4; ++kk) {
            short8 af[4], bfr[4];
            #pragma unroll
            for (int mt = 0; mt < 4; ++mt)
                af[mt] = *(const short8*)&aln[(mt * 16 + ln15) * 136 + kk * 32 + q8];
            #pragma unroll
            for (int nt = 0; nt < 4; ++nt)
                bfr[nt] = *(const short8*)(p1w + kk * 2048 + nt * 512 + lane * 8);
            #pragma unroll
            for (int mt = 0; mt < 4; ++mt)
                #pragma unroll
                for (int nt = 0; nt < 4; ++nt)
                    acc[mt][nt] = __builtin_amdgcn_mfma_f32_16x16x32_bf16(
                        af[mt], bfr[nt], acc[mt][nt], 0, 0, 0);
        }
        if (cc) __syncthreads();
        #pragma unroll
        for (int mt = 0; mt < 4; ++mt)
            #pragma unroll
            for (int nt = 0; nt < 4; ++nt)
                #pragma unroll
                for (int r = 0; r < 4; ++r) {
                    int m = mt * 16 + quad * 4 + r;
                    int ncl = wv * 64 + nt * 16 + ln15;
                    float v = acc[mt][nt][r] + b1[cc * 256 + ncl];
                    v = 0.5f * v * (1.0f + erff(v * 0.70710678118654752f));
                    hidc[m * 264 + ncl] = __float2bfloat16(v);
                }
        __syncthreads();
        const bf16* p2w = pw2 + (size_t)(wv * 2 + cc) * 8192;
        #pragma unroll
        for (int ks = 0; ks < 8; ++ks) {
            short8 af[4], bfr[2];
            #pragma unroll
            for (int mt = 0; mt < 4; ++mt)
                af[mt] = *(const short8*)&hidc[(mt * 16 + ln15) * 264 + ks * 32 + q8];
            #pragma unroll
            for (int nt = 0; nt < 2; ++nt)
                bfr[nt] = *(const short8*)(p2w + ks * 1024 + nt * 512 + lane * 8);
            #pragma unroll
            for (int mt = 0; mt < 4; ++mt)
                #pragma unroll
                for (int nt = 0; nt < 2; ++nt)
                    acc2[mt][nt] = __builtin_amdgcn_mfma_f32_16x16x32_bf16(
                        af[mt], bfr[nt], acc2[mt][nt], 0, 0, 0);
        }
    }
    __syncthreads();

    #pragma unroll
    for (int mt = 0; mt < 4; ++mt)
        #pragma unroll
        for (int nt = 0; nt < 2; ++nt)
            #pragma unroll
            for (int r = 0; r < 4; ++r) {
                int m = mt * 16 + quad * 4 + r;
                int n = wv * 32 + nt * 16 + ln15;
                ostage[m * 132 + n] = acc2[mt][nt][r] + b2[n];
            }
    __syncthreads();

    #pragma unroll
    for (int jj = 0; jj < 8; ++jj) {
        int idx = (jj * 256 + tid) * 4;
        int t = idx >> 7, c = idx & 127;
        float4 v = *(const float4*)(xbuf + tok0 * 128 + idx);
        float4 o = *(const float4*)&ostage[t * 132 + c];
        v.x += o.x; v.y += o.y; v.z += o.z; v.w += o.w;
        *(float4*)(xbuf + tok0 * 128 + idx) = v;
        if (xout16) {
            __align__(8) bf16 hh[4];
            hh[0] = __float2bfloat16(v.x); hh[1] = __float2bfloat16(v.y);
            hh[2] = __float2bfloat16(v.z); hh[3] = __float2bfloat16(v.w);
            *(uint2*)(xout16 + tok0 * 128 + idx) = *(const uint2*)hh;
        }
    }
}

// ---------------------------------------------------------------------------
// Windowed attention v3: one block per window, 512 threads = 8 waves = 8 heads.
// Stages the window's full [64][384] qkv slab into LDS with coalesced loads
// (each 64B line fetched exactly once); per-head k/v reads are wave-uniform
// LDS broadcasts (conflict-free). qkv is row-major [tok][384].
// ---------------------------------------------------------------------------
__global__ __launch_bounds__(512) void attn_kernel(
    const bf16* __restrict__ qkv, const float* __restrict__ rpbt,
    bf16* __restrict__ outp, int shift)
{
    __shared__ __align__(16) short qs[64 * 392];   // 50176 B, row stride 392
    __shared__ float rp[2744];                     // [head][343]
    __shared__ int   cnt[64];
    int tid = threadIdx.x;
    int lw  = blockIdx.x;                          // global window 0..1023
    int h   = tid >> 6;                            // head = wave
    int i   = tid & 63;                            // query token (lane)

    // stage qkv slab: 64 rows x 48 uint4-chunks, fully coalesced
    #pragma unroll
    for (int p = 0; p < 6; ++p) {
        int idx = p * 512 + tid;                   // 0..3071
        int row = idx / 48, ch = idx - row * 48;
        *(uint4*)&qs[row * 392 + ch * 8] =
            *(const uint4*)(qkv + ((size_t)(lw * 64) + row) * 384 + ch * 8);
    }
    for (int j = tid; j < 2744; j += 512) rp[j] = rpbt[j];
    if (shift && tid < 64) {
        int w = lw & 511;
        int ihh = tid >> 4, iww = (tid >> 2) & 3, itt = tid & 3;
        int wh = w >> 6, ww = (w >> 3) & 7, wt = w & 7;
        int hh = wh * 4 + ihh, w2 = ww * 4 + iww, t = wt * 4 + itt;
        int rh = (hh < 28) ? 0 : ((hh < 30) ? 1 : 2);
        int rw = (w2 < 28) ? 0 : ((w2 < 30) ? 1 : 2);
        int rt = (t  < 28) ? 0 : ((t  < 30) ? 1 : 2);
        cnt[tid] = (rh * 3 + rw) * 3 + rt;
    }
    __syncthreads();

    // per-lane q (registers)
    float q[16];
    {
        short8 q0 = *(const short8*)&qs[i * 392 + h * 16];
        short8 q1 = *(const short8*)&qs[i * 392 + h * 16 + 8];
        #pragma unroll
        for (int d = 0; d < 8; ++d) {
            q[d]     = b2f(q0[d]) * 0.25f;
            q[d + 8] = b2f(q1[d]) * 0.25f;
        }
    }
    int ih = i >> 4, iw = (i >> 2) & 3, it = i & 3;
    int ci = shift ? cnt[i] : 0;
    const float* rph = rp + h * 343;

    float logits[64];
    #pragma unroll
    for (int j = 0; j < 64; ++j) {
        short8 k0 = *(const short8*)&qs[j * 392 + 128 + h * 16];      // broadcast
        short8 k1 = *(const short8*)&qs[j * 392 + 136 + h * 16];
        float d0 = 0.f;
        #pragma unroll
        for (int d = 0; d < 8; ++d)
            d0 += q[d] * b2f(k0[d]) + q[d + 8] * b2f(k1[d]);
        int jh = j >> 4, jw = (j >> 2) & 3, jt = j & 3;
        int ridx = ((ih - jh + 3) * 7 + (iw - jw + 3)) * 7 + (it - jt + 3);
        d0 += rph[ridx];
        if (shift && cnt[j] != ci) d0 -= 100.0f;
        logits[j] = d0;
    }
    float mx = -1e30f;
    #pragma unroll
    for (int j = 0; j < 64; ++j) mx = fmaxf(mx, logits[j]);
    float ssum = 0.f;
    #pragma unroll
    for (int j = 0; j < 64; ++j) { float e = __expf(logits[j] - mx); logits[j] = e; ssum += e; }
    float inv = 1.0f / ssum;
    float o[16] = {};
    #pragma unroll
    for (int j = 0; j < 64; ++j) {
        float p = logits[j] * inv;
        short8 v0 = *(const short8*)&qs[j * 392 + 256 + h * 16];      // broadcast
        short8 v1 = *(const short8*)&qs[j * 392 + 264 + h * 16];
        #pragma unroll
        for (int d = 0; d < 8; ++d) {
            o[d]     += p * b2f(v0[d]);
            o[d + 8] += p * b2f(v1[d]);
        }
    }
    bf16* op = outp + (size_t)(lw * 64 + i) * 128 + h * 16;
    __align__(16) bf16 ob[16];
    #pragma unroll
    for (int d = 0; d < 16; ++d) ob[d] = __float2bfloat16(o[d]);
    *(uint4*)op       = *(const uint4*)&ob[0];
    *(uint4*)(op + 8) = *(const uint4*)&ob[8];
}

// ---------------------------------------------------------------------------
// Depthwise 3x3x3 conv, bf16 in/out, register t-window reuse.
// ---------------------------------------------------------------------------
__global__ __launch_bounds__(512) void dwconv_kernel(
    const bf16* __restrict__ x, const float* __restrict__ dwt,
    const float* __restrict__ bias, bf16* __restrict__ out)
{
    int blk = blockIdx.x;
    int b = blk >> 10;
    int h = (blk >> 5) & 31;
    int w = blk & 31;
    int tid = threadIdx.x;
    int c = tid & 127;
    int t0 = (tid >> 7) * 8;
    float acc[8];
    float bs = bias[c];
    #pragma unroll
    for (int o = 0; o < 8; ++o) acc[o] = bs;
    #pragma unroll
    for (int kh = 0; kh < 3; ++kh) {
        int hh = h + kh - 1;
        if (hh < 0 || hh > 31) continue;
        #pragma unroll
        for (int kw = 0; kw < 3; ++kw) {
            int ww = w + kw - 1;
            if (ww < 0 || ww > 31) continue;
            const bf16* px = x + (((size_t)(b << 15) + (hh * 32 + ww) * 32) * 128) + c;
            float v[10];
            #pragma unroll
            for (int u = 0; u < 10; ++u) {
                int tt = t0 - 1 + u;
                v[u] = (tt >= 0 && tt < 32) ? __bfloat162float(px[(size_t)tt * 128]) : 0.f;
            }
            float w0 = dwt[((kh * 3 + kw) * 3 + 0) * 128 + c];
            float w1 = dwt[((kh * 3 + kw) * 3 + 1) * 128 + c];
            float w2 = dwt[((kh * 3 + kw) * 3 + 2) * 128 + c];
            #pragma unroll
            for (int o = 0; o < 8; ++o)
                acc[o] += v[o] * w0 + v[o + 1] * w1 + v[o + 2] * w2;
        }
    }
    bf16* po = out + (((size_t)(b << 15) + (h * 32 + w) * 32 + t0) * 128) + c;
    #pragma unroll
    for (int o = 0; o < 8; ++o) po[(size_t)o * 128] = __float2bfloat16(acc[o]);
}

// ---------------------------------------------------------------------------
extern "C" void kernel_launch(void* const* d_in, const int* in_sizes, int n_in,
                              void* d_out, int out_size, void* d_ws, size_t ws_size,
                              hipStream_t stream)
{
    const float* x_in    = (const float*)d_in[0];
    const float* norm1_g = (const float*)d_in[1];
    const float* norm1_b = (const float*)d_in[2];
    const float* qkv_w   = (const float*)d_in[3];
    const float* qkv_b   = (const float*)d_in[4];
    const float* proj_w  = (const float*)d_in[5];
    const float* proj_b  = (const float*)d_in[6];
    const float* rpb     = (const float*)d_in[7];
    const float* norm2_g = (const float*)d_in[8];
    const float* norm2_b = (const float*)d_in[9];
    const float* fc1_w   = (const float*)d_in[10];
    const float* fc1_b   = (const float*)d_in[11];
    const float* fc2_w   = (const float*)d_in[12];
    const float* fc2_b   = (const float*)d_in[13];
    const float* dw_w    = (const float*)d_in[14];
    const float* dw_b    = (const float*)d_in[15];
    const float* pw_w    = (const float*)d_in[16];
    const float* pw_b    = (const float*)d_in[17];
    const float* bn_g    = (const float*)d_in[18];
    const float* bn_b    = (const float*)d_in[19];
    float* out = (float*)d_out;

    char* ws = (char*)d_ws;
    float* xbuf   = (float*)ws;                          // [0,32MB)   fp32 [TOK,128]
    bf16*  wbf    = (bf16*)(ws + 33554432ULL);           // [32,34MB)  bf16 weights
    float* dwt    = (float*)(ws + 35651584ULL);          // 27x128 fp32
    float* stats  = (float*)(ws + 35717120ULL);          // 2 KB
    bf16*  pw1    = (bf16*)(ws + 35782656ULL);           // 512 KB packed fc1
    bf16*  pw2    = (bf16*)(ws + 36306944ULL);           // 512 KB packed fc2
    float* rpbt   = (float*)(ws + 36831232ULL);          // 44 KB
    bf16*  lnbuf  = (bf16*)(ws + 37748736ULL);           // [36,52MB)  [TOK,128]
    bf16*  attnbuf= (bf16*)(ws + 54525952ULL);           // [52,68MB)  [TOK,128]
    bf16*  qkvbuf = (bf16*)(ws + 71303168ULL);           // [68,116MB) [TOK,384]
    bf16*  dwbuf  = attnbuf;
    bf16*  dcbuf  = lnbuf;

    bf16* wqkv  = wbf;                 // 4 x 384 x 128
    bf16* wproj = wbf + 196608;        // 4 x 128 x 128
    bf16* wpw   = wbf + 786432;        // 256 x 128

    hipLaunchKernelGGL(prep_kernel, dim3(3200), dim3(256), 0, stream,
                       qkv_w, proj_w, fc1_w, fc2_w, pw_w, dw_w, wbf, dwt, stats);
    hipLaunchKernelGGL(pack_kernel, dim3(2048), dim3(256), 0, stream,
                       fc1_w, fc2_w, rpb, pw1, pw2, rpbt);
    hipLaunchKernelGGL(transpose_in_kernel, dim3(1024), dim3(256), 0, stream, x_in, xbuf);

    const int shifts[4] = {0, 2, 0, 2};
    for (int i = 0; i < 4; ++i) {
        int s = shifts[i];
        // --- attention half ---
        hipLaunchKernelGGL(ln_window_kernel, dim3(TOK / 4), dim3(256), 0, stream,
                           xbuf, lnbuf, norm1_g + i * 128, norm1_b + i * 128, s);
        hipLaunchKernelGGL(gemm_bf16_kernel, dim3(3, TOK / 128), dim3(256), 0, stream,
                           lnbuf, wqkv + (size_t)i * 49152, qkv_b + i * 384,
                           qkvbuf, (float*)nullptr, (float*)nullptr,
                           (const float*)nullptr, (const float*)nullptr,
                           TOK, 384, 128, 0, 0);
        hipLaunchKernelGGL(attn_kernel, dim3(1024), dim3(512), 0, stream,
                           qkvbuf, rpbt + i * 2744, attnbuf, s);
        hipLaunchKernelGGL(gemm_bf16_kernel, dim3(1, TOK / 128), dim3(256), 0, stream,
                           attnbuf, wproj + (size_t)i * 16384, proj_b + i * 128,
                           (bf16*)nullptr, (float*)nullptr, xbuf,
                           (const float*)nullptr, (const float*)nullptr,
                           TOK, 128, 128, 2, s);
        // --- fused MLP ---
        hipLaunchKernelGGL(mlp_kernel, dim3(TOK / 64), dim3(256), 0, stream,
                           xbuf, norm2_g + i * 128, norm2_b + i * 128,
                           pw1 + (size_t)i * 65536, fc1_b + i * 512,
                           pw2 + (size_t)i * 65536, fc2_b + i * 128,
                           (i == 3) ? dwbuf : (bf16*)nullptr);
    }

    // connectBlock
    hipLaunchKernelGGL(dwconv_kernel, dim3(2048), dim3(512), 0, stream,
                       dwbuf, dwt, dw_b, dcbuf);
    hipLaunchKernelGGL(gemm_bf16_kernel, dim3(OUTC / 128, TOK / 128), dim3(256), 0, stream,
                       dcbuf, wpw, pw_b,
                       (bf16*)nullptr, (float*)nullptr, stats,
                       (const float*)nullptr, (const float*)nullptr,
                       TOK, OUTC, 128, 4, 0);
    hipLaunchKernelGGL(gemm_bf16_kernel, dim3(OUTC / 128, TOK / 128), dim3(256), 0, stream,
                       dcbuf, wpw, pw_b,
                       (bf16*)nullptr, out, stats,
                       bn_g, bn_b,
                       TOK, OUTC, 128, 5, 0);
}